// Round 3
// baseline (1086.813 us; speedup 1.0000x reference)
//
#include <hip/hip_runtime.h>
#include <cstdint>

#define DEVI __device__ __forceinline__

typedef int v4i __attribute__((ext_vector_type(4)));
typedef short v8s __attribute__((ext_vector_type(8)));
typedef float v4f __attribute__((ext_vector_type(4)));

// ---------- bf16 helpers (manual, RNE) ----------
DEVI float bf_lo(unsigned u) { return __uint_as_float(u << 16); }
DEVI float bf_hi(unsigned u) { return __uint_as_float(u & 0xffff0000u); }
DEVI float bf2f(unsigned short h) { return __uint_as_float(((unsigned)h) << 16); }
DEVI unsigned short f2bf(float f) {
  unsigned u = __float_as_uint(f);
  u += 0x7fffu + ((u >> 16) & 1u);
  return (unsigned short)(u >> 16);
}

// ---------- async global->LDS, 16B per lane (lane i lands at base + i*16) ----------
DEVI void async_copy16(void* l, const void* g) {
  __builtin_amdgcn_global_load_lds((const __attribute__((address_space(1))) void*)g,
                                   (__attribute__((address_space(3))) void*)l,
                                   16, 0, 0);
}

// ---------- wave (64-lane) reductions ----------
DEVI float wave_sum(float v) {
#pragma unroll
  for (int o = 32; o > 0; o >>= 1) v += __shfl_xor(v, o, 64);
  return v;
}
DEVI float wave_max(float v) {
#pragma unroll
  for (int o = 32; o > 0; o >>= 1) v = fmaxf(v, __shfl_xor(v, o, 64));
  return v;
}

// ---------- per-tensor sum(|w|) ----------
__global__ __launch_bounds__(256) void absum_kernel(const float* __restrict__ w, long n,
                                                    float* __restrict__ acc) {
  long stride = (long)gridDim.x * 1024;
  float s = 0.f;
  for (long i = ((long)blockIdx.x * 256 + threadIdx.x) * 4; i < n; i += stride) {
    float4 v = *(const float4*)(w + i);
    s += fabsf(v.x) + fabsf(v.y) + fabsf(v.z) + fabsf(v.w);
  }
  s = wave_sum(s);
  __shared__ float sc[4];
  int tid = threadIdx.x;
  if ((tid & 63) == 0) sc[tid >> 6] = s;
  __syncthreads();
  if (tid == 0) atomicAdd(acc, sc[0] + sc[1] + sc[2] + sc[3]);
}

// ---------- ternary weight quant: q = clamp(round(w/ws), -1, 1) ----------
__global__ __launch_bounds__(256) void wquant_kernel(const float* __restrict__ w, long n4,
                                                     const float* __restrict__ acc, float cnt,
                                                     signed char* __restrict__ out) {
  float wsv = fmaxf(acc[0] / cnt, 1e-5f);
  float inv = 1.0f / wsv;
  long stride = (long)gridDim.x * 256;
  for (long i = (long)blockIdx.x * 256 + threadIdx.x; i < n4; i += stride) {
    float4 v = *(const float4*)(w + i * 4);
    int q0 = max(-1, min(1, (int)rintf(v.x * inv)));
    int q1 = max(-1, min(1, (int)rintf(v.y * inv)));
    int q2 = max(-1, min(1, (int)rintf(v.z * inv)));
    int q3 = max(-1, min(1, (int)rintf(v.w * inv)));
    unsigned r = (q0 & 0xff) | ((q1 & 0xff) << 8) | ((q2 & 0xff) << 16) | ((q3 & 0xff) << 24);
    ((unsigned*)out)[i] = r;
  }
}

// ---------- fused LayerNorm + per-token absmax int8 quant (C=2048, 1 block/row) ----------
__global__ __launch_bounds__(256) void ln_quant_kernel(const float* __restrict__ x,
                                                       const float* __restrict__ g,
                                                       const float* __restrict__ b,
                                                       signed char* __restrict__ q,
                                                       float* __restrict__ inv_s) {
  int row = blockIdx.x, tid = threadIdx.x;
  const float4* xr = (const float4*)(x + (long)row * 2048);
  float4 a0 = xr[tid * 2], a1 = xr[tid * 2 + 1];
  float xv[8] = {a0.x, a0.y, a0.z, a0.w, a1.x, a1.y, a1.z, a1.w};
  float s = 0.f, s2 = 0.f;
#pragma unroll
  for (int e = 0; e < 8; ++e) { s += xv[e]; s2 += xv[e] * xv[e]; }
  s = wave_sum(s); s2 = wave_sum(s2);
  __shared__ float sc[8];
  if ((tid & 63) == 0) { sc[tid >> 6] = s; sc[4 + (tid >> 6)] = s2; }
  __syncthreads();
  float mean = (sc[0] + sc[1] + sc[2] + sc[3]) * (1.f / 2048.f);
  float var = (sc[4] + sc[5] + sc[6] + sc[7]) * (1.f / 2048.f) - mean * mean;
  float rs = 1.0f / sqrtf(var + 1e-5f);
  float4 g0 = ((const float4*)g)[tid * 2], g1v = ((const float4*)g)[tid * 2 + 1];
  float4 b0 = ((const float4*)b)[tid * 2], b1v = ((const float4*)b)[tid * 2 + 1];
  float gv[8] = {g0.x, g0.y, g0.z, g0.w, g1v.x, g1v.y, g1v.z, g1v.w};
  float bv[8] = {b0.x, b0.y, b0.z, b0.w, b1v.x, b1v.y, b1v.z, b1v.w};
  float y[8];
  float am = 0.f;
#pragma unroll
  for (int e = 0; e < 8; ++e) {
    y[e] = (xv[e] - mean) * rs * gv[e] + bv[e];
    am = fmaxf(am, fabsf(y[e]));
  }
  am = wave_max(am);
  __syncthreads();
  if ((tid & 63) == 0) sc[tid >> 6] = am;
  __syncthreads();
  am = fmaxf(fmaxf(sc[0], sc[1]), fmaxf(sc[2], sc[3]));
  float c = fmaxf(am, 1e-5f);
  float xs = 127.0f / c;
  union { signed char c8[8]; int2 v; } u;
#pragma unroll
  for (int e = 0; e < 8; ++e) {
    int t = (int)rintf(y[e] * xs);
    u.c8[e] = (signed char)max(-128, min(127, t));
  }
  ((int2*)(q + (long)row * 2048))[tid] = u.v;
  if (tid == 0) inv_s[row] = c * (1.0f / 127.0f);
}

// ---------- per-row absmax int8 quant from bf16 rows (R = 2048 or 8192) ----------
template <int R>
__global__ __launch_bounds__(256) void row_quant_kernel(const unsigned short* __restrict__ in,
                                                        signed char* __restrict__ q,
                                                        float* __restrict__ inv_s) {
  constexpr int V = R / 2048;  // uint4 (8 elems) per thread
  int row = blockIdx.x, tid = threadIdx.x;
  const uint4* p = (const uint4*)(in + (long)row * R);
  float y[V * 8];
  float am = 0.f;
#pragma unroll
  for (int v = 0; v < V; ++v) {
    uint4 d = p[tid * V + v];
    unsigned xw[4] = {d.x, d.y, d.z, d.w};
#pragma unroll
    for (int k = 0; k < 4; ++k) {
      y[v * 8 + k * 2] = bf_lo(xw[k]);
      y[v * 8 + k * 2 + 1] = bf_hi(xw[k]);
    }
  }
#pragma unroll
  for (int e = 0; e < V * 8; ++e) am = fmaxf(am, fabsf(y[e]));
  am = wave_max(am);
  __shared__ float sc[4];
  if ((tid & 63) == 0) sc[tid >> 6] = am;
  __syncthreads();
  am = fmaxf(fmaxf(sc[0], sc[1]), fmaxf(sc[2], sc[3]));
  float c = fmaxf(am, 1e-5f);
  float xs = 127.0f / c;
  signed char* qr = q + (long)row * R;
#pragma unroll
  for (int v = 0; v < V; ++v) {
    union { signed char c8[8]; long l; } u;
#pragma unroll
    for (int k = 0; k < 8; ++k) {
      int t = (int)rintf(y[v * 8 + k] * xs);
      u.c8[k] = (signed char)max(-128, min(127, t));
    }
    ((long*)qr)[tid * V + v] = u.l;
  }
  if (tid == 0) inv_s[row] = c * (1.0f / 127.0f);
}

// ---------- int8 MFMA GEMM, v2: A double-buffered in LDS (1 barrier/iter),
// B (ternary weights, L2-resident) direct global->VGPR with register prefetch.
// out[M,N] = (A[M,K]i8 . B[N,K]i8^T) * ws * inv_s[m] (+epilogue)
// EPI 0: bf16 store   EPI 1: fp32 store + residual   EPI 2: bf16 store of exact GELU
template <int EPI>
__global__ __launch_bounds__(256)
void gemm_i8(const signed char* __restrict__ A, const signed char* __restrict__ B,
             int N, int K, const float* __restrict__ wacc, float wcount,
             const float* __restrict__ inv_s, const float* __restrict__ res,
             void* __restrict__ outp) {
  __shared__ signed char As[2][128 * 64];
  int tid = threadIdx.x;
  int m0 = blockIdx.y * 128, n0 = blockIdx.x * 128;
  int w = tid >> 6, lane = tid & 63;
  int wm = (w >> 1) * 64, wn = (w & 1) * 64;
  int lr = lane & 15, lk = (lane >> 4) * 16;

  v4i acc[4][4] = {};

  // A staging: 512 chunks of 16B per tile; wave w owns chunks [128w,128w+128), 2 instrs
  int u0 = w * 128 + lane;
  int u1 = u0 + 64;
  const signed char* ga0 = A + (long)(m0 + (u0 >> 2)) * K + (u0 & 3) * 16;
  const signed char* ga1 = A + (long)(m0 + (u1 >> 2)) * K + (u1 & 3) * 16;
  int la0 = (w * 128) * 16;       // wave-uniform LDS offsets
  int la1 = (w * 128 + 64) * 16;

  // B row pointers (direct from global/L2)
  const signed char* gb[4];
#pragma unroll
  for (int t = 0; t < 4; ++t) gb[t] = B + (long)(n0 + wn + t * 16 + lr) * K + lk;

  // prologue: stage A(0), load B(0)
  async_copy16((char*)As[0] + la0, ga0);
  async_copy16((char*)As[0] + la1, ga1);
  v4i bf_cur[4], bf_nxt[4];
#pragma unroll
  for (int t = 0; t < 4; ++t) bf_cur[t] = *(const v4i*)(gb[t]);
  __syncthreads();

  int buf = 0;
  for (int kk = 0; kk < K; kk += 64) {
    if (kk + 64 < K) {
      // stage next A tile into the other buffer; prefetch next B frags
      async_copy16((char*)As[buf ^ 1] + la0, ga0 + kk + 64);
      async_copy16((char*)As[buf ^ 1] + la1, ga1 + kk + 64);
#pragma unroll
      for (int t = 0; t < 4; ++t) bf_nxt[t] = *(const v4i*)(gb[t] + kk + 64);
    }
    v4i af[4];
#pragma unroll
    for (int t = 0; t < 4; ++t) af[t] = *(const v4i*)(As[buf] + (wm + t * 16 + lr) * 64 + lk);
#pragma unroll
    for (int i = 0; i < 4; ++i)
#pragma unroll
      for (int j = 0; j < 4; ++j)
        acc[i][j] = __builtin_amdgcn_mfma_i32_16x16x64_i8(af[i], bf_cur[j], acc[i][j], 0, 0, 0);
    __syncthreads();  // all reads of As[buf] done; As[buf^1] staging landed (vmcnt drain)
#pragma unroll
    for (int t = 0; t < 4; ++t) bf_cur[t] = bf_nxt[t];
    buf ^= 1;
  }

  float wsv = fmaxf(wacc[0] / wcount, 1e-5f);
#pragma unroll
  for (int i = 0; i < 4; ++i) {
    int rowbase = m0 + wm + i * 16 + (lane >> 4) * 4;
#pragma unroll
    for (int r = 0; r < 4; ++r) {
      int row = rowbase + r;
      float s = wsv * inv_s[row];
#pragma unroll
      for (int j = 0; j < 4; ++j) {
        int col = n0 + wn + j * 16 + (lane & 15);
        long off = (long)row * N + col;
        float v = (float)acc[i][j][r] * s;
        if constexpr (EPI == 0) {
          ((unsigned short*)outp)[off] = f2bf(v);
        } else if constexpr (EPI == 1) {
          ((float*)outp)[off] = v + res[off];
        } else {
          float gvv = 0.5f * v * (1.0f + erff(v * 0.70710678118654752f));
          ((unsigned short*)outp)[off] = f2bf(gvv);
        }
      }
    }
  }
}

// ---------- MFMA flash attention ----------
__global__ __launch_bounds__(256)
void fattn_kernel(const unsigned short* __restrict__ qkv, unsigned short* __restrict__ o) {
  constexpr int VROW = 72;
  constexpr int PROW = 72;
  __shared__ char Ks[16384];
  __shared__ unsigned short Vt[128 * VROW];
  __shared__ unsigned short Ps[4 * 16 * PROW];

  int tid = threadIdx.x;
  int w = tid >> 6, lane = tid & 63;
  int l = lane & 15, q = lane >> 4;
  int qt = blockIdx.x, bh = blockIdx.y;
  int bb = bh >> 4, hh = bh & 15;
  const unsigned short* base = qkv + (long)bb * 2048 * 6144;
  int q0 = qt * 64;

  v8s aq[4];
  {
    const unsigned short* qrow = base + (long)(q0 + w * 16 + l) * 6144 + hh * 128;
#pragma unroll
    for (int kf = 0; kf < 4; ++kf) aq[kf] = *(const v8s*)(qrow + kf * 32 + q * 8);
  }

  v4f oacc[8];
#pragma unroll
  for (int t = 0; t < 8; ++t) oacc[t] = (v4f){0.f, 0.f, 0.f, 0.f};
  float mrow[4], lrow[4];
#pragma unroll
  for (int r = 0; r < 4; ++r) { mrow[r] = -1e30f; lrow[r] = 0.f; }

  unsigned short* pw = Ps + w * 16 * PROW;
  const unsigned short* kbase_g = base + 2048 + hh * 128;
  const unsigned short* vbase_g = base + 4096 + hh * 128;
  int kg = tid & 7, dg = tid >> 3;
  constexpr float SC = 0.08838834764831845f;

  for (int kt = 0; kt < 32; ++kt) {
    int k0 = kt * 64;
#pragma unroll
    for (int i = 0; i < 4; ++i) {
      int c = i * 256 + w * 64 + lane;
      int key = c >> 4;
      int dch = (c & 15) ^ (key & 15);
      async_copy16(Ks + (i * 256 + w * 64) * 16,
                   kbase_g + (long)(k0 + key) * 6144 + dch * 8);
    }
    {
      uint2 lv[8];
#pragma unroll
      for (int i = 0; i < 8; ++i)
        lv[i] = *(const uint2*)(vbase_g + (long)(k0 + kg * 8 + i) * 6144 + dg * 4);
#pragma unroll
      for (int jd = 0; jd < 4; ++jd) {
        v8s pk;
#pragma unroll
        for (int i = 0; i < 8; ++i) {
          unsigned word = (jd < 2) ? lv[i].x : lv[i].y;
          pk[i] = (short)((jd & 1) ? (word >> 16) : (word & 0xffffu));
        }
        *(v8s*)(Vt + (dg * 4 + jd) * VROW + kg * 8) = pk;
      }
    }
    __syncthreads();

    v4f sacc[4];
#pragma unroll
    for (int t = 0; t < 4; ++t) sacc[t] = (v4f){0.f, 0.f, 0.f, 0.f};
#pragma unroll
    for (int kf = 0; kf < 4; ++kf) {
#pragma unroll
      for (int t = 0; t < 4; ++t) {
        int ch = (t * 16 + l) * 16 + ((kf * 4 + q) ^ l);
        v8s bk = *(const v8s*)(Ks + ch * 16);
        sacc[t] = __builtin_amdgcn_mfma_f32_16x16x32_bf16(aq[kf], bk, sacc[t], 0, 0, 0);
      }
    }
    float rmax[4], alpha[4], rsum[4];
#pragma unroll
    for (int r = 0; r < 4; ++r) {
      rmax[r] = fmaxf(fmaxf(sacc[0][r], sacc[1][r]), fmaxf(sacc[2][r], sacc[3][r])) * SC;
#pragma unroll
      for (int msk = 1; msk < 16; msk <<= 1) rmax[r] = fmaxf(rmax[r], __shfl_xor(rmax[r], msk, 64));
      float mnew = fmaxf(mrow[r], rmax[r]);
      alpha[r] = __expf(mrow[r] - mnew);
      mrow[r] = mnew;
      rsum[r] = 0.f;
    }
#pragma unroll
    for (int t = 0; t < 4; ++t) {
#pragma unroll
      for (int r = 0; r < 4; ++r) {
        float p = __expf(sacc[t][r] * SC - mrow[r]);
        rsum[r] += p;
        pw[(q * 4 + r) * PROW + t * 16 + l] = f2bf(p);
      }
    }
#pragma unroll
    for (int r = 0; r < 4; ++r) {
#pragma unroll
      for (int msk = 1; msk < 16; msk <<= 1) rsum[r] += __shfl_xor(rsum[r], msk, 64);
      lrow[r] = lrow[r] * alpha[r] + rsum[r];
#pragma unroll
      for (int t = 0; t < 8; ++t) oacc[t][r] *= alpha[r];
    }
#pragma unroll
    for (int s2 = 0; s2 < 2; ++s2) {
      v8s ap = *(const v8s*)(pw + l * PROW + s2 * 32 + q * 8);
#pragma unroll
      for (int t = 0; t < 8; ++t) {
        v8s bv = *(const v8s*)(Vt + (t * 16 + l) * VROW + s2 * 32 + q * 8);
        oacc[t] = __builtin_amdgcn_mfma_f32_16x16x32_bf16(ap, bv, oacc[t], 0, 0, 0);
      }
    }
    __syncthreads();
  }

#pragma unroll
  for (int t = 0; t < 8; ++t) {
#pragma unroll
    for (int r = 0; r < 4; ++r) {
      float val = oacc[t][r] / lrow[r];
      o[((long)(bb * 2048 + q0 + w * 16 + q * 4 + r)) * 2048 + hh * 128 + t * 16 + l] = f2bf(val);
    }
  }
}

extern "C" void kernel_launch(void* const* d_in, const int* in_sizes, int n_in,
                              void* d_out, int out_size, void* d_ws, size_t ws_size,
                              hipStream_t stream) {
  (void)in_sizes; (void)n_in; (void)out_size; (void)ws_size;
  const float* x      = (const float*)d_in[0];
  const float* w_qkv  = (const float*)d_in[1];
  const float* w_proj = (const float*)d_in[2];
  const float* w_fc1  = (const float*)d_in[3];
  const float* w_fc2  = (const float*)d_in[4];
  const float* g1 = (const float*)d_in[5];
  const float* b1 = (const float*)d_in[6];
  const float* g2 = (const float*)d_in[7];
  const float* b2 = (const float*)d_in[8];

  char* wsb = (char*)d_ws;
  float* acc = (float*)wsb;
  size_t off = 256;
  signed char* q8 = (signed char*)(wsb + off);       off += (size_t)4096 * 8192;
  float* invs = (float*)(wsb + off);                 off += 16384;
  signed char* wq_qkv = (signed char*)(wsb + off);   off += (size_t)6144 * 2048;
  signed char* wq_proj = (signed char*)(wsb + off);  off += (size_t)2048 * 2048;
  signed char* wq_fc1 = (signed char*)(wsb + off);   off += (size_t)8192 * 2048;
  signed char* wq_fc2 = (signed char*)(wsb + off);   off += (size_t)2048 * 8192;
  unsigned short* qkvh = (unsigned short*)(wsb + off); off += (size_t)4096 * 8192 * 2;
  unsigned short* obuf = (unsigned short*)(wsb + off); off += (size_t)4096 * 2048 * 2;
  float* x2 = (float*)(wsb + off);                   off += (size_t)4096 * 2048 * 4;

  hipMemsetAsync(acc, 0, 256, stream);

  absum_kernel<<<dim3(1024), 256, 0, stream>>>(w_qkv, (long)6144 * 2048, acc + 0);
  absum_kernel<<<dim3(512),  256, 0, stream>>>(w_proj, (long)2048 * 2048, acc + 1);
  absum_kernel<<<dim3(1024), 256, 0, stream>>>(w_fc1, (long)8192 * 2048, acc + 2);
  absum_kernel<<<dim3(1024), 256, 0, stream>>>(w_fc2, (long)2048 * 8192, acc + 3);

  wquant_kernel<<<dim3(1024), 256, 0, stream>>>(w_qkv, (long)6144 * 2048 / 4, acc + 0, 12582912.f, wq_qkv);
  wquant_kernel<<<dim3(1024), 256, 0, stream>>>(w_proj, (long)2048 * 2048 / 4, acc + 1, 4194304.f, wq_proj);
  wquant_kernel<<<dim3(1024), 256, 0, stream>>>(w_fc1, (long)8192 * 2048 / 4, acc + 2, 16777216.f, wq_fc1);
  wquant_kernel<<<dim3(1024), 256, 0, stream>>>(w_fc2, (long)2048 * 8192 / 4, acc + 3, 16777216.f, wq_fc2);

  ln_quant_kernel<<<4096, 256, 0, stream>>>(x, g1, b1, q8, invs);
  gemm_i8<0><<<dim3(48, 32), 256, 0, stream>>>(q8, wq_qkv, 6144, 2048, acc + 0, 12582912.f, invs, nullptr, qkvh);
  fattn_kernel<<<dim3(32, 32), 256, 0, stream>>>(qkvh, obuf);
  row_quant_kernel<2048><<<4096, 256, 0, stream>>>(obuf, q8, invs);
  gemm_i8<1><<<dim3(16, 32), 256, 0, stream>>>(q8, wq_proj, 2048, 2048, acc + 1, 4194304.f, invs, x, x2);
  ln_quant_kernel<<<4096, 256, 0, stream>>>(x2, g2, b2, q8, invs);
  gemm_i8<2><<<dim3(64, 32), 256, 0, stream>>>(q8, wq_fc1, 8192, 2048, acc + 2, 16777216.f, invs, nullptr, qkvh);
  row_quant_kernel<8192><<<4096, 256, 0, stream>>>(qkvh, q8, invs);
  gemm_i8<1><<<dim3(16, 32), 256, 0, stream>>>(q8, wq_fc2, 2048, 8192, acc + 3, 16777216.f, invs, x2, (float*)d_out);
}

// Round 4
// 876.835 us; speedup vs baseline: 1.2395x; 1.2395x over previous
//
#include <hip/hip_runtime.h>
#include <cstdint>

#define DEVI __device__ __forceinline__

typedef int v4i __attribute__((ext_vector_type(4)));
typedef short v8s __attribute__((ext_vector_type(8)));
typedef float v4f __attribute__((ext_vector_type(4)));

// ---------- bf16 helpers (manual, RNE) ----------
DEVI float bf_lo(unsigned u) { return __uint_as_float(u << 16); }
DEVI float bf_hi(unsigned u) { return __uint_as_float(u & 0xffff0000u); }
DEVI float bf2f(unsigned short h) { return __uint_as_float(((unsigned)h) << 16); }
DEVI unsigned short f2bf(float f) {
  unsigned u = __float_as_uint(f);
  u += 0x7fffu + ((u >> 16) & 1u);
  return (unsigned short)(u >> 16);
}

// ---------- async global->LDS, 16B per lane (lane i lands at base + i*16) ----------
DEVI void async_copy16(void* l, const void* g) {
  __builtin_amdgcn_global_load_lds((const __attribute__((address_space(1))) void*)g,
                                   (__attribute__((address_space(3))) void*)l,
                                   16, 0, 0);
}

// ---------- wave (64-lane) reductions ----------
DEVI float wave_sum(float v) {
#pragma unroll
  for (int o = 32; o > 0; o >>= 1) v += __shfl_xor(v, o, 64);
  return v;
}
DEVI float wave_max(float v) {
#pragma unroll
  for (int o = 32; o > 0; o >>= 1) v = fmaxf(v, __shfl_xor(v, o, 64));
  return v;
}

// ---------- per-tensor sum(|w|) ----------
__global__ __launch_bounds__(256) void absum_kernel(const float* __restrict__ w, long n,
                                                    float* __restrict__ acc) {
  long stride = (long)gridDim.x * 1024;
  float s = 0.f;
  for (long i = ((long)blockIdx.x * 256 + threadIdx.x) * 4; i < n; i += stride) {
    float4 v = *(const float4*)(w + i);
    s += fabsf(v.x) + fabsf(v.y) + fabsf(v.z) + fabsf(v.w);
  }
  s = wave_sum(s);
  __shared__ float sc[4];
  int tid = threadIdx.x;
  if ((tid & 63) == 0) sc[tid >> 6] = s;
  __syncthreads();
  if (tid == 0) atomicAdd(acc, sc[0] + sc[1] + sc[2] + sc[3]);
}

// ---------- ternary weight quant: q = clamp(round(w/ws), -1, 1) ----------
__global__ __launch_bounds__(256) void wquant_kernel(const float* __restrict__ w, long n4,
                                                     const float* __restrict__ acc, float cnt,
                                                     signed char* __restrict__ out) {
  float wsv = fmaxf(acc[0] / cnt, 1e-5f);
  float inv = 1.0f / wsv;
  long stride = (long)gridDim.x * 256;
  for (long i = (long)blockIdx.x * 256 + threadIdx.x; i < n4; i += stride) {
    float4 v = *(const float4*)(w + i * 4);
    int q0 = max(-1, min(1, (int)rintf(v.x * inv)));
    int q1 = max(-1, min(1, (int)rintf(v.y * inv)));
    int q2 = max(-1, min(1, (int)rintf(v.z * inv)));
    int q3 = max(-1, min(1, (int)rintf(v.w * inv)));
    unsigned r = (q0 & 0xff) | ((q1 & 0xff) << 8) | ((q2 & 0xff) << 16) | ((q3 & 0xff) << 24);
    ((unsigned*)out)[i] = r;
  }
}

// ---------- fused LayerNorm + per-token absmax int8 quant (C=2048, 1 block/row) ----------
__global__ __launch_bounds__(256) void ln_quant_kernel(const float* __restrict__ x,
                                                       const float* __restrict__ g,
                                                       const float* __restrict__ b,
                                                       signed char* __restrict__ q,
                                                       float* __restrict__ inv_s) {
  int row = blockIdx.x, tid = threadIdx.x;
  const float4* xr = (const float4*)(x + (long)row * 2048);
  float4 a0 = xr[tid * 2], a1 = xr[tid * 2 + 1];
  float xv[8] = {a0.x, a0.y, a0.z, a0.w, a1.x, a1.y, a1.z, a1.w};
  float s = 0.f, s2 = 0.f;
#pragma unroll
  for (int e = 0; e < 8; ++e) { s += xv[e]; s2 += xv[e] * xv[e]; }
  s = wave_sum(s); s2 = wave_sum(s2);
  __shared__ float sc[8];
  if ((tid & 63) == 0) { sc[tid >> 6] = s; sc[4 + (tid >> 6)] = s2; }
  __syncthreads();
  float mean = (sc[0] + sc[1] + sc[2] + sc[3]) * (1.f / 2048.f);
  float var = (sc[4] + sc[5] + sc[6] + sc[7]) * (1.f / 2048.f) - mean * mean;
  float rs = 1.0f / sqrtf(var + 1e-5f);
  float4 g0 = ((const float4*)g)[tid * 2], g1v = ((const float4*)g)[tid * 2 + 1];
  float4 b0 = ((const float4*)b)[tid * 2], b1v = ((const float4*)b)[tid * 2 + 1];
  float gv[8] = {g0.x, g0.y, g0.z, g0.w, g1v.x, g1v.y, g1v.z, g1v.w};
  float bv[8] = {b0.x, b0.y, b0.z, b0.w, b1v.x, b1v.y, b1v.z, b1v.w};
  float y[8];
  float am = 0.f;
#pragma unroll
  for (int e = 0; e < 8; ++e) {
    y[e] = (xv[e] - mean) * rs * gv[e] + bv[e];
    am = fmaxf(am, fabsf(y[e]));
  }
  am = wave_max(am);
  __syncthreads();
  if ((tid & 63) == 0) sc[tid >> 6] = am;
  __syncthreads();
  am = fmaxf(fmaxf(sc[0], sc[1]), fmaxf(sc[2], sc[3]));
  float c = fmaxf(am, 1e-5f);
  float xs = 127.0f / c;
  union { signed char c8[8]; int2 v; } u;
#pragma unroll
  for (int e = 0; e < 8; ++e) {
    int t = (int)rintf(y[e] * xs);
    u.c8[e] = (signed char)max(-128, min(127, t));
  }
  ((int2*)(q + (long)row * 2048))[tid] = u.v;
  if (tid == 0) inv_s[row] = c * (1.0f / 127.0f);
}

// ---------- per-row absmax int8 quant from bf16 rows (R = 2048 or 8192) ----------
template <int R>
__global__ __launch_bounds__(256) void row_quant_kernel(const unsigned short* __restrict__ in,
                                                        signed char* __restrict__ q,
                                                        float* __restrict__ inv_s) {
  constexpr int V = R / 2048;  // uint4 (8 elems) per thread
  int row = blockIdx.x, tid = threadIdx.x;
  const uint4* p = (const uint4*)(in + (long)row * R);
  float y[V * 8];
  float am = 0.f;
#pragma unroll
  for (int v = 0; v < V; ++v) {
    uint4 d = p[tid * V + v];
    unsigned xw[4] = {d.x, d.y, d.z, d.w};
#pragma unroll
    for (int k = 0; k < 4; ++k) {
      y[v * 8 + k * 2] = bf_lo(xw[k]);
      y[v * 8 + k * 2 + 1] = bf_hi(xw[k]);
    }
  }
#pragma unroll
  for (int e = 0; e < V * 8; ++e) am = fmaxf(am, fabsf(y[e]));
  am = wave_max(am);
  __shared__ float sc[4];
  if ((tid & 63) == 0) sc[tid >> 6] = am;
  __syncthreads();
  am = fmaxf(fmaxf(sc[0], sc[1]), fmaxf(sc[2], sc[3]));
  float c = fmaxf(am, 1e-5f);
  float xs = 127.0f / c;
  signed char* qr = q + (long)row * R;
#pragma unroll
  for (int v = 0; v < V; ++v) {
    union { signed char c8[8]; long l; } u;
#pragma unroll
    for (int k = 0; k < 8; ++k) {
      int t = (int)rintf(y[v * 8 + k] * xs);
      u.c8[k] = (signed char)max(-128, min(127, t));
    }
    ((long*)qr)[tid * V + v] = u.l;
  }
  if (tid == 0) inv_s[row] = c * (1.0f / 127.0f);
}

// ---------- int8 MFMA GEMM (R2-proven version: A+B staged via global_load_lds, 2 barriers)
// out[M,N] = (A[M,K]i8 . B[N,K]i8^T) * ws * inv_s[m] (+epilogue)
// EPI 0: bf16 store   EPI 1: fp32 store + residual   EPI 2: bf16 store of exact GELU
template <int EPI>
__global__ __launch_bounds__(256)
void gemm_i8(const signed char* __restrict__ A, const signed char* __restrict__ B,
             int N, int K, const float* __restrict__ wacc, float wcount,
             const float* __restrict__ inv_s, const float* __restrict__ res,
             void* __restrict__ outp) {
  __shared__ signed char As[128 * 64];
  __shared__ signed char Bs[128 * 64];
  int tid = threadIdx.x;
  int m0 = blockIdx.y * 128, n0 = blockIdx.x * 128;
  int w = tid >> 6, lane = tid & 63;
  int wm = (w >> 1) * 64, wn = (w & 1) * 64;
  int lr = lane & 15, lk = (lane >> 4) * 16;

  v4i acc[4][4] = {};

  int u0 = w * 128 + lane;
  int u1 = u0 + 64;
  const signed char* ga0 = A + (long)(m0 + (u0 >> 2)) * K + (u0 & 3) * 16;
  const signed char* ga1 = A + (long)(m0 + (u1 >> 2)) * K + (u1 & 3) * 16;
  const signed char* gb0 = B + (long)(n0 + (u0 >> 2)) * K + (u0 & 3) * 16;
  const signed char* gb1 = B + (long)(n0 + (u1 >> 2)) * K + (u1 & 3) * 16;
  char* la0 = (char*)As + (w * 128) * 16;
  char* la1 = (char*)As + (w * 128 + 64) * 16;
  char* lb0 = (char*)Bs + (w * 128) * 16;
  char* lb1 = (char*)Bs + (w * 128 + 64) * 16;

  for (int kk = 0; kk < K; kk += 64) {
    async_copy16(la0, ga0 + kk);
    async_copy16(la1, ga1 + kk);
    async_copy16(lb0, gb0 + kk);
    async_copy16(lb1, gb1 + kk);
    __syncthreads();
    v4i af[4], bf[4];
#pragma unroll
    for (int t = 0; t < 4; ++t) af[t] = *(const v4i*)(As + (wm + t * 16 + lr) * 64 + lk);
#pragma unroll
    for (int t = 0; t < 4; ++t) bf[t] = *(const v4i*)(Bs + (wn + t * 16 + lr) * 64 + lk);
#pragma unroll
    for (int i = 0; i < 4; ++i)
#pragma unroll
      for (int j = 0; j < 4; ++j)
        acc[i][j] = __builtin_amdgcn_mfma_i32_16x16x64_i8(af[i], bf[j], acc[i][j], 0, 0, 0);
    __syncthreads();
  }

  float wsv = fmaxf(wacc[0] / wcount, 1e-5f);
#pragma unroll
  for (int i = 0; i < 4; ++i) {
    int rowbase = m0 + wm + i * 16 + (lane >> 4) * 4;
#pragma unroll
    for (int r = 0; r < 4; ++r) {
      int row = rowbase + r;
      float s = wsv * inv_s[row];
#pragma unroll
      for (int j = 0; j < 4; ++j) {
        int col = n0 + wn + j * 16 + (lane & 15);
        long off = (long)row * N + col;
        float v = (float)acc[i][j][r] * s;
        if constexpr (EPI == 0) {
          ((unsigned short*)outp)[off] = f2bf(v);
        } else if constexpr (EPI == 1) {
          ((float*)outp)[off] = v + res[off];
        } else {
          float gvv = 0.5f * v * (1.0f + erff(v * 0.70710678118654752f));
          ((unsigned short*)outp)[off] = f2bf(gvv);
        }
      }
    }
  }
}

// ---------- MFMA flash attention v2: 128 Q-rows/block, 32 Q-rows/wave ----------
// Every bk/bv LDS fragment read is reused across two A-frags; K/V staging amortized 2x.
__global__ __launch_bounds__(256, 2)
void fattn_kernel(const unsigned short* __restrict__ qkv, unsigned short* __restrict__ o) {
  constexpr int VROW = 72;
  constexpr int PROW = 72;
  __shared__ char Ks[16384];                  // 64 keys x 128 dim bf16, chunk-swizzled
  __shared__ unsigned short Vt[128 * VROW];   // transposed V tile
  __shared__ unsigned short Ps[4 * 32 * PROW];

  int tid = threadIdx.x;
  int w = tid >> 6, lane = tid & 63;
  int l = lane & 15, q = lane >> 4;
  int qt = blockIdx.x, bh = blockIdx.y;
  int bb = bh >> 4, hh = bh & 15;
  const unsigned short* base = qkv + (long)bb * 2048 * 6144;
  int q0 = qt * 128;

  // Q fragments (A-layout) for two 16-row sets: rows q0 + w*32 + s*16 + l
  v8s aq[2][4];
#pragma unroll
  for (int s = 0; s < 2; ++s) {
    const unsigned short* qrow = base + (long)(q0 + w * 32 + s * 16 + l) * 6144 + hh * 128;
#pragma unroll
    for (int kf = 0; kf < 4; ++kf) aq[s][kf] = *(const v8s*)(qrow + kf * 32 + q * 8);
  }

  v4f oacc[2][8];
#pragma unroll
  for (int s = 0; s < 2; ++s)
#pragma unroll
    for (int t = 0; t < 8; ++t) oacc[s][t] = (v4f){0.f, 0.f, 0.f, 0.f};
  float mrow[2][4], lrow[2][4];
#pragma unroll
  for (int s = 0; s < 2; ++s)
#pragma unroll
    for (int r = 0; r < 4; ++r) { mrow[s][r] = -1e30f; lrow[s][r] = 0.f; }

  unsigned short* pw = Ps + w * 32 * PROW;
  const unsigned short* kbase_g = base + 2048 + hh * 128;
  const unsigned short* vbase_g = base + 4096 + hh * 128;
  int kg = tid & 7, dg = tid >> 3;  // V staging: thread -> 8 keys x 4 dims
  constexpr float SC = 0.08838834764831845f;  // 1/sqrt(128)

  for (int kt = 0; kt < 32; ++kt) {
    int k0 = kt * 64;
    // --- stage K tile (swizzled chunks: (key,dch) -> LDS chunk key*16 + (dch^key&15)) ---
#pragma unroll
    for (int i = 0; i < 4; ++i) {
      int c = i * 256 + w * 64 + lane;
      int key = c >> 4;
      int dch = (c & 15) ^ (key & 15);
      async_copy16(Ks + (i * 256 + w * 64) * 16,
                   kbase_g + (long)(k0 + key) * 6144 + dch * 8);
    }
    // --- stage V transposed ---
    {
      uint2 lv[8];
#pragma unroll
      for (int i = 0; i < 8; ++i)
        lv[i] = *(const uint2*)(vbase_g + (long)(k0 + kg * 8 + i) * 6144 + dg * 4);
#pragma unroll
      for (int jd = 0; jd < 4; ++jd) {
        v8s pk;
#pragma unroll
        for (int i = 0; i < 8; ++i) {
          unsigned word = (jd < 2) ? lv[i].x : lv[i].y;
          pk[i] = (short)((jd & 1) ? (word >> 16) : (word & 0xffffu));
        }
        *(v8s*)(Vt + (dg * 4 + jd) * VROW + kg * 8) = pk;
      }
    }
    __syncthreads();  // drains async K (vmcnt) + Vt writes (lgkmcnt)

    // --- S = Q K^T, both row-sets share each bk read ---
    v4f sacc[2][4];
#pragma unroll
    for (int s = 0; s < 2; ++s)
#pragma unroll
      for (int t = 0; t < 4; ++t) sacc[s][t] = (v4f){0.f, 0.f, 0.f, 0.f};
#pragma unroll
    for (int kf = 0; kf < 4; ++kf) {
#pragma unroll
      for (int t = 0; t < 4; ++t) {
        int ch = (t * 16 + l) * 16 + ((kf * 4 + q) ^ l);
        v8s bk = *(const v8s*)(Ks + ch * 16);
        sacc[0][t] = __builtin_amdgcn_mfma_f32_16x16x32_bf16(aq[0][kf], bk, sacc[0][t], 0, 0, 0);
        sacc[1][t] = __builtin_amdgcn_mfma_f32_16x16x32_bf16(aq[1][kf], bk, sacc[1][t], 0, 0, 0);
      }
    }
    // --- online softmax (per row-set) ---
#pragma unroll
    for (int s = 0; s < 2; ++s) {
      float rmax[4], alpha[4], rsum[4];
#pragma unroll
      for (int r = 0; r < 4; ++r) {
        rmax[r] = fmaxf(fmaxf(sacc[s][0][r], sacc[s][1][r]),
                        fmaxf(sacc[s][2][r], sacc[s][3][r])) * SC;
#pragma unroll
        for (int msk = 1; msk < 16; msk <<= 1) rmax[r] = fmaxf(rmax[r], __shfl_xor(rmax[r], msk, 64));
        float mnew = fmaxf(mrow[s][r], rmax[r]);
        alpha[r] = __expf(mrow[s][r] - mnew);
        mrow[s][r] = mnew;
        rsum[r] = 0.f;
      }
#pragma unroll
      for (int t = 0; t < 4; ++t) {
#pragma unroll
        for (int r = 0; r < 4; ++r) {
          float p = __expf(sacc[s][t][r] * SC - mrow[s][r]);
          rsum[r] += p;
          pw[(s * 16 + q * 4 + r) * PROW + t * 16 + l] = f2bf(p);
        }
      }
#pragma unroll
      for (int r = 0; r < 4; ++r) {
#pragma unroll
        for (int msk = 1; msk < 16; msk <<= 1) rsum[r] += __shfl_xor(rsum[r], msk, 64);
        lrow[s][r] = lrow[s][r] * alpha[r] + rsum[r];
#pragma unroll
        for (int t = 0; t < 8; ++t) oacc[s][t][r] *= alpha[r];
      }
    }
    // --- O += P V, both row-sets share each bv read ---
#pragma unroll
    for (int s2 = 0; s2 < 2; ++s2) {
      v8s ap0 = *(const v8s*)(pw + l * PROW + s2 * 32 + q * 8);
      v8s ap1 = *(const v8s*)(pw + (16 + l) * PROW + s2 * 32 + q * 8);
#pragma unroll
      for (int t = 0; t < 8; ++t) {
        v8s bv = *(const v8s*)(Vt + (t * 16 + l) * VROW + s2 * 32 + q * 8);
        oacc[0][t] = __builtin_amdgcn_mfma_f32_16x16x32_bf16(ap0, bv, oacc[0][t], 0, 0, 0);
        oacc[1][t] = __builtin_amdgcn_mfma_f32_16x16x32_bf16(ap1, bv, oacc[1][t], 0, 0, 0);
      }
    }
    __syncthreads();  // all waves done with Ks/Vt/Ps before restage
  }

  // --- epilogue: O / l, bf16 store ---
#pragma unroll
  for (int s = 0; s < 2; ++s) {
#pragma unroll
    for (int t = 0; t < 8; ++t) {
#pragma unroll
      for (int r = 0; r < 4; ++r) {
        float val = oacc[s][t][r] / lrow[s][r];
        o[((long)(bb * 2048 + q0 + w * 32 + s * 16 + q * 4 + r)) * 2048 + hh * 128 + t * 16 + l] =
            f2bf(val);
      }
    }
  }
}

extern "C" void kernel_launch(void* const* d_in, const int* in_sizes, int n_in,
                              void* d_out, int out_size, void* d_ws, size_t ws_size,
                              hipStream_t stream) {
  (void)in_sizes; (void)n_in; (void)out_size; (void)ws_size;
  const float* x      = (const float*)d_in[0];
  const float* w_qkv  = (const float*)d_in[1];
  const float* w_proj = (const float*)d_in[2];
  const float* w_fc1  = (const float*)d_in[3];
  const float* w_fc2  = (const float*)d_in[4];
  const float* g1 = (const float*)d_in[5];
  const float* b1 = (const float*)d_in[6];
  const float* g2 = (const float*)d_in[7];
  const float* b2 = (const float*)d_in[8];

  char* wsb = (char*)d_ws;
  float* acc = (float*)wsb;
  size_t off = 256;
  signed char* q8 = (signed char*)(wsb + off);       off += (size_t)4096 * 8192;
  float* invs = (float*)(wsb + off);                 off += 16384;
  signed char* wq_qkv = (signed char*)(wsb + off);   off += (size_t)6144 * 2048;
  signed char* wq_proj = (signed char*)(wsb + off);  off += (size_t)2048 * 2048;
  signed char* wq_fc1 = (signed char*)(wsb + off);   off += (size_t)8192 * 2048;
  signed char* wq_fc2 = (signed char*)(wsb + off);   off += (size_t)2048 * 8192;
  unsigned short* qkvh = (unsigned short*)(wsb + off); off += (size_t)4096 * 8192 * 2;
  unsigned short* obuf = (unsigned short*)(wsb + off); off += (size_t)4096 * 2048 * 2;
  float* x2 = (float*)(wsb + off);                   off += (size_t)4096 * 2048 * 4;

  hipMemsetAsync(acc, 0, 256, stream);

  absum_kernel<<<dim3(1024), 256, 0, stream>>>(w_qkv, (long)6144 * 2048, acc + 0);
  absum_kernel<<<dim3(512),  256, 0, stream>>>(w_proj, (long)2048 * 2048, acc + 1);
  absum_kernel<<<dim3(1024), 256, 0, stream>>>(w_fc1, (long)8192 * 2048, acc + 2);
  absum_kernel<<<dim3(1024), 256, 0, stream>>>(w_fc2, (long)2048 * 8192, acc + 3);

  wquant_kernel<<<dim3(1024), 256, 0, stream>>>(w_qkv, (long)6144 * 2048 / 4, acc + 0, 12582912.f, wq_qkv);
  wquant_kernel<<<dim3(1024), 256, 0, stream>>>(w_proj, (long)2048 * 2048 / 4, acc + 1, 4194304.f, wq_proj);
  wquant_kernel<<<dim3(1024), 256, 0, stream>>>(w_fc1, (long)8192 * 2048 / 4, acc + 2, 16777216.f, wq_fc1);
  wquant_kernel<<<dim3(1024), 256, 0, stream>>>(w_fc2, (long)2048 * 8192 / 4, acc + 3, 16777216.f, wq_fc2);

  ln_quant_kernel<<<4096, 256, 0, stream>>>(x, g1, b1, q8, invs);
  gemm_i8<0><<<dim3(48, 32), 256, 0, stream>>>(q8, wq_qkv, 6144, 2048, acc + 0, 12582912.f, invs, nullptr, qkvh);
  fattn_kernel<<<dim3(16, 32), 256, 0, stream>>>(qkvh, obuf);
  row_quant_kernel<2048><<<4096, 256, 0, stream>>>(obuf, q8, invs);
  gemm_i8<1><<<dim3(16, 32), 256, 0, stream>>>(q8, wq_proj, 2048, 2048, acc + 1, 4194304.f, invs, x, x2);
  ln_quant_kernel<<<4096, 256, 0, stream>>>(x2, g2, b2, q8, invs);
  gemm_i8<2><<<dim3(64, 32), 256, 0, stream>>>(q8, wq_fc1, 8192, 2048, acc + 2, 16777216.f, invs, nullptr, qkvh);
  row_quant_kernel<8192><<<4096, 256, 0, stream>>>(qkvh, q8, invs);
  gemm_i8<1><<<dim3(16, 32), 256, 0, stream>>>(q8, wq_fc2, 2048, 8192, acc + 3, 16777216.f, invs, x2, (float*)d_out);
}

// Round 5
// 875.867 us; speedup vs baseline: 1.2408x; 1.0011x over previous
//
#include <hip/hip_runtime.h>
#include <cstdint>

#define DEVI __device__ __forceinline__

typedef int v4i __attribute__((ext_vector_type(4)));
typedef short v8s __attribute__((ext_vector_type(8)));
typedef float v4f __attribute__((ext_vector_type(4)));

// ---------- bf16 helpers (manual, RNE) ----------
DEVI float bf_lo(unsigned u) { return __uint_as_float(u << 16); }
DEVI float bf_hi(unsigned u) { return __uint_as_float(u & 0xffff0000u); }
DEVI float bf2f(unsigned short h) { return __uint_as_float(((unsigned)h) << 16); }
DEVI unsigned short f2bf(float f) {
  unsigned u = __float_as_uint(f);
  u += 0x7fffu + ((u >> 16) & 1u);
  return (unsigned short)(u >> 16);
}

// ---------- async global->LDS, 16B per lane (lane i lands at base + i*16) ----------
DEVI void async_copy16(void* l, const void* g) {
  __builtin_amdgcn_global_load_lds((const __attribute__((address_space(1))) void*)g,
                                   (__attribute__((address_space(3))) void*)l,
                                   16, 0, 0);
}

// ---------- wave (64-lane) reductions ----------
DEVI float wave_sum(float v) {
#pragma unroll
  for (int o = 32; o > 0; o >>= 1) v += __shfl_xor(v, o, 64);
  return v;
}
DEVI float wave_max(float v) {
#pragma unroll
  for (int o = 32; o > 0; o >>= 1) v = fmaxf(v, __shfl_xor(v, o, 64));
  return v;
}

// ---------- per-tensor sum(|w|) ----------
__global__ __launch_bounds__(256) void absum_kernel(const float* __restrict__ w, long n,
                                                    float* __restrict__ acc) {
  long stride = (long)gridDim.x * 1024;
  float s = 0.f;
  for (long i = ((long)blockIdx.x * 256 + threadIdx.x) * 4; i < n; i += stride) {
    float4 v = *(const float4*)(w + i);
    s += fabsf(v.x) + fabsf(v.y) + fabsf(v.z) + fabsf(v.w);
  }
  s = wave_sum(s);
  __shared__ float sc[4];
  int tid = threadIdx.x;
  if ((tid & 63) == 0) sc[tid >> 6] = s;
  __syncthreads();
  if (tid == 0) atomicAdd(acc, sc[0] + sc[1] + sc[2] + sc[3]);
}

// ---------- ternary weight quant into MFMA-fragment-major packed layout ----------
// packed block for (ntile, kb): 1024 B; chunk lane = (kgrp<<4)|(n&15) holds
// B[n][kb*64 + kgrp*16 .. +16]. A wave's b-frag load = contiguous 1 KB.
__global__ __launch_bounds__(256) void wquant_kernel(const float* __restrict__ w, long n4,
                                                     const float* __restrict__ acc, float cnt,
                                                     signed char* __restrict__ out, int kshift) {
  float wsv = fmaxf(acc[0] / cnt, 1e-5f);
  float inv = 1.0f / wsv;
  int K = 1 << kshift;
  long stride = (long)gridDim.x * 256;
  for (long i = (long)blockIdx.x * 256 + threadIdx.x; i < n4; i += stride) {
    float4 v = *(const float4*)(w + i * 4);
    int q0 = max(-1, min(1, (int)rintf(v.x * inv)));
    int q1 = max(-1, min(1, (int)rintf(v.y * inv)));
    int q2 = max(-1, min(1, (int)rintf(v.z * inv)));
    int q3 = max(-1, min(1, (int)rintf(v.w * inv)));
    unsigned r = (q0 & 0xff) | ((q1 & 0xff) << 8) | ((q2 & 0xff) << 16) | ((q3 & 0xff) << 24);
    long flat = i * 4;
    int n = (int)(flat >> kshift);
    int k = (int)(flat & (K - 1));
    long off = ((long)(n >> 4) * (K >> 6) + (k >> 6)) * 1024 +
               (((k >> 4) & 3) * 16 + (n & 15)) * 16 + (k & 15);
    *(unsigned*)(out + off) = r;
  }
}

// ---------- fused LayerNorm + per-token absmax int8 quant (C=2048, 1 block/row) ----------
__global__ __launch_bounds__(256) void ln_quant_kernel(const float* __restrict__ x,
                                                       const float* __restrict__ g,
                                                       const float* __restrict__ b,
                                                       signed char* __restrict__ q,
                                                       float* __restrict__ inv_s) {
  int row = blockIdx.x, tid = threadIdx.x;
  const float4* xr = (const float4*)(x + (long)row * 2048);
  float4 a0 = xr[tid * 2], a1 = xr[tid * 2 + 1];
  float xv[8] = {a0.x, a0.y, a0.z, a0.w, a1.x, a1.y, a1.z, a1.w};
  float s = 0.f, s2 = 0.f;
#pragma unroll
  for (int e = 0; e < 8; ++e) { s += xv[e]; s2 += xv[e] * xv[e]; }
  s = wave_sum(s); s2 = wave_sum(s2);
  __shared__ float sc[8];
  if ((tid & 63) == 0) { sc[tid >> 6] = s; sc[4 + (tid >> 6)] = s2; }
  __syncthreads();
  float mean = (sc[0] + sc[1] + sc[2] + sc[3]) * (1.f / 2048.f);
  float var = (sc[4] + sc[5] + sc[6] + sc[7]) * (1.f / 2048.f) - mean * mean;
  float rs = 1.0f / sqrtf(var + 1e-5f);
  float4 g0 = ((const float4*)g)[tid * 2], g1v = ((const float4*)g)[tid * 2 + 1];
  float4 b0 = ((const float4*)b)[tid * 2], b1v = ((const float4*)b)[tid * 2 + 1];
  float gv[8] = {g0.x, g0.y, g0.z, g0.w, g1v.x, g1v.y, g1v.z, g1v.w};
  float bv[8] = {b0.x, b0.y, b0.z, b0.w, b1v.x, b1v.y, b1v.z, b1v.w};
  float y[8];
  float am = 0.f;
#pragma unroll
  for (int e = 0; e < 8; ++e) {
    y[e] = (xv[e] - mean) * rs * gv[e] + bv[e];
    am = fmaxf(am, fabsf(y[e]));
  }
  am = wave_max(am);
  __syncthreads();
  if ((tid & 63) == 0) sc[tid >> 6] = am;
  __syncthreads();
  am = fmaxf(fmaxf(sc[0], sc[1]), fmaxf(sc[2], sc[3]));
  float c = fmaxf(am, 1e-5f);
  float xs = 127.0f / c;
  union { signed char c8[8]; int2 v; } u;
#pragma unroll
  for (int e = 0; e < 8; ++e) {
    int t = (int)rintf(y[e] * xs);
    u.c8[e] = (signed char)max(-128, min(127, t));
  }
  ((int2*)(q + (long)row * 2048))[tid] = u.v;
  if (tid == 0) inv_s[row] = c * (1.0f / 127.0f);
}

// ---------- per-row absmax int8 quant from bf16 rows (R = 2048 or 8192) ----------
template <int R>
__global__ __launch_bounds__(256) void row_quant_kernel(const unsigned short* __restrict__ in,
                                                        signed char* __restrict__ q,
                                                        float* __restrict__ inv_s) {
  constexpr int V = R / 2048;
  int row = blockIdx.x, tid = threadIdx.x;
  const uint4* p = (const uint4*)(in + (long)row * R);
  float y[V * 8];
  float am = 0.f;
#pragma unroll
  for (int v = 0; v < V; ++v) {
    uint4 d = p[tid * V + v];
    unsigned xw[4] = {d.x, d.y, d.z, d.w};
#pragma unroll
    for (int k = 0; k < 4; ++k) {
      y[v * 8 + k * 2] = bf_lo(xw[k]);
      y[v * 8 + k * 2 + 1] = bf_hi(xw[k]);
    }
  }
#pragma unroll
  for (int e = 0; e < V * 8; ++e) am = fmaxf(am, fabsf(y[e]));
  am = wave_max(am);
  __shared__ float sc[4];
  if ((tid & 63) == 0) sc[tid >> 6] = am;
  __syncthreads();
  am = fmaxf(fmaxf(sc[0], sc[1]), fmaxf(sc[2], sc[3]));
  float c = fmaxf(am, 1e-5f);
  float xs = 127.0f / c;
  signed char* qr = q + (long)row * R;
#pragma unroll
  for (int v = 0; v < V; ++v) {
    union { signed char c8[8]; long l; } u;
#pragma unroll
    for (int k = 0; k < 8; ++k) {
      int t = (int)rintf(y[v * 8 + k] * xs);
      u.c8[k] = (signed char)max(-128, min(127, t));
    }
    ((long*)qr)[tid * V + v] = u.l;
  }
  if (tid == 0) inv_s[row] = c * (1.0f / 127.0f);
}

// ---------- int8 MFMA GEMM v3: A dbuf in LDS (1 barrier/iter),
// B from packed-fragment layout: coalesced 1KB global loads, prefetched 1 iter ahead.
template <int EPI>
__global__ __launch_bounds__(256)
void gemm_i8(const signed char* __restrict__ A, const signed char* __restrict__ Bp,
             int N, int K, const float* __restrict__ wacc, float wcount,
             const float* __restrict__ inv_s, const float* __restrict__ res,
             void* __restrict__ outp) {
  __shared__ signed char As[2][128 * 64];
  int tid = threadIdx.x;
  int m0 = blockIdx.y * 128, n0 = blockIdx.x * 128;
  int w = tid >> 6, lane = tid & 63;
  int wm = (w >> 1) * 64, wn = (w & 1) * 64;
  int lr = lane & 15, lk = (lane >> 4) * 16;

  v4i acc[4][4] = {};

  // A staging: 512 chunks of 16B per tile; wave w owns 128 chunks, 2 instrs
  int u0 = w * 128 + lane;
  int u1 = u0 + 64;
  const signed char* ga0 = A + (long)(m0 + (u0 >> 2)) * K + (u0 & 3) * 16;
  const signed char* ga1 = A + (long)(m0 + (u1 >> 2)) * K + (u1 & 3) * 16;
  int la0 = (w * 128) * 16;
  int la1 = (w * 128 + 64) * 16;

  // B packed-fragment base pointers: one contiguous 1KB per (ntile, kb)
  int kb64 = K >> 6;
  const signed char* gbp[4];
#pragma unroll
  for (int t = 0; t < 4; ++t) {
    int ntile = (n0 >> 4) + (w & 1) * 4 + t;
    gbp[t] = Bp + (long)ntile * kb64 * 1024 + lane * 16;
  }

  // prologue
  async_copy16((char*)As[0] + la0, ga0);
  async_copy16((char*)As[0] + la1, ga1);
  v4i bf_cur[4], bf_nxt[4];
#pragma unroll
  for (int t = 0; t < 4; ++t) bf_cur[t] = *(const v4i*)(gbp[t]);
  __syncthreads();

  int buf = 0;
  for (int kb = 0; kb < kb64; ++kb) {
    if (kb + 1 < kb64) {
      async_copy16((char*)As[buf ^ 1] + la0, ga0 + (kb + 1) * 64);
      async_copy16((char*)As[buf ^ 1] + la1, ga1 + (kb + 1) * 64);
#pragma unroll
      for (int t = 0; t < 4; ++t) bf_nxt[t] = *(const v4i*)(gbp[t] + (kb + 1) * 1024);
    }
    v4i af[4];
#pragma unroll
    for (int t = 0; t < 4; ++t) af[t] = *(const v4i*)(As[buf] + (wm + t * 16 + lr) * 64 + lk);
#pragma unroll
    for (int i = 0; i < 4; ++i)
#pragma unroll
      for (int j = 0; j < 4; ++j)
        acc[i][j] = __builtin_amdgcn_mfma_i32_16x16x64_i8(af[i], bf_cur[j], acc[i][j], 0, 0, 0);
    __syncthreads();  // As[buf] reads done; next-tile copies (in flight during MFMA) drained
#pragma unroll
    for (int t = 0; t < 4; ++t) bf_cur[t] = bf_nxt[t];
    buf ^= 1;
  }

  float wsv = fmaxf(wacc[0] / wcount, 1e-5f);
#pragma unroll
  for (int i = 0; i < 4; ++i) {
    int rowbase = m0 + wm + i * 16 + (lane >> 4) * 4;
#pragma unroll
    for (int r = 0; r < 4; ++r) {
      int row = rowbase + r;
      float s = wsv * inv_s[row];
#pragma unroll
      for (int j = 0; j < 4; ++j) {
        int col = n0 + wn + j * 16 + (lane & 15);
        long off = (long)row * N + col;
        float v = (float)acc[i][j][r] * s;
        if constexpr (EPI == 0) {
          ((unsigned short*)outp)[off] = f2bf(v);
        } else if constexpr (EPI == 1) {
          ((float*)outp)[off] = v + res[off];
        } else {
          float gvv = 0.5f * v * (1.0f + erff(v * 0.70710678118654752f));
          ((unsigned short*)outp)[off] = f2bf(gvv);
        }
      }
    }
  }
}

// ---------- MFMA flash attention, K-split partials (flash-decoding) ----------
// grid (16 qt, 32 bh, 2 ks): each block does 16 k-tiles, writes unnormalized O (fp32) + (m,l).
__global__ __launch_bounds__(256, 2)
void fattn_kernel(const unsigned short* __restrict__ qkv, float* __restrict__ O0,
                  float* __restrict__ O1, float2* __restrict__ stats) {
  constexpr int VROW = 72;
  constexpr int PROW = 72;
  __shared__ char Ks[16384];
  __shared__ unsigned short Vt[128 * VROW];
  __shared__ unsigned short Ps[4 * 32 * PROW];

  int tid = threadIdx.x;
  int w = tid >> 6, lane = tid & 63;
  int l = lane & 15, q = lane >> 4;
  int qt = blockIdx.x, bh = blockIdx.y, ks = blockIdx.z;
  int bb = bh >> 4, hh = bh & 15;
  const unsigned short* base = qkv + (long)bb * 2048 * 6144;
  int q0 = qt * 128;
  float* Opart = ks ? O1 : O0;

  v8s aq[2][4];
#pragma unroll
  for (int s = 0; s < 2; ++s) {
    const unsigned short* qrow = base + (long)(q0 + w * 32 + s * 16 + l) * 6144 + hh * 128;
#pragma unroll
    for (int kf = 0; kf < 4; ++kf) aq[s][kf] = *(const v8s*)(qrow + kf * 32 + q * 8);
  }

  v4f oacc[2][8];
#pragma unroll
  for (int s = 0; s < 2; ++s)
#pragma unroll
    for (int t = 0; t < 8; ++t) oacc[s][t] = (v4f){0.f, 0.f, 0.f, 0.f};
  float mrow[2][4], lrow[2][4];
#pragma unroll
  for (int s = 0; s < 2; ++s)
#pragma unroll
    for (int r = 0; r < 4; ++r) { mrow[s][r] = -1e30f; lrow[s][r] = 0.f; }

  unsigned short* pw = Ps + w * 32 * PROW;
  const unsigned short* kbase_g = base + 2048 + hh * 128;
  const unsigned short* vbase_g = base + 4096 + hh * 128;
  int kg = tid & 7, dg = tid >> 3;
  constexpr float SC = 0.08838834764831845f;

  for (int kt = ks * 16; kt < ks * 16 + 16; ++kt) {
    int k0 = kt * 64;
#pragma unroll
    for (int i = 0; i < 4; ++i) {
      int c = i * 256 + w * 64 + lane;
      int key = c >> 4;
      int dch = (c & 15) ^ (key & 15);
      async_copy16(Ks + (i * 256 + w * 64) * 16,
                   kbase_g + (long)(k0 + key) * 6144 + dch * 8);
    }
    {
      uint2 lv[8];
#pragma unroll
      for (int i = 0; i < 8; ++i)
        lv[i] = *(const uint2*)(vbase_g + (long)(k0 + kg * 8 + i) * 6144 + dg * 4);
#pragma unroll
      for (int jd = 0; jd < 4; ++jd) {
        v8s pk;
#pragma unroll
        for (int i = 0; i < 8; ++i) {
          unsigned word = (jd < 2) ? lv[i].x : lv[i].y;
          pk[i] = (short)((jd & 1) ? (word >> 16) : (word & 0xffffu));
        }
        *(v8s*)(Vt + (dg * 4 + jd) * VROW + kg * 8) = pk;
      }
    }
    __syncthreads();

    v4f sacc[2][4];
#pragma unroll
    for (int s = 0; s < 2; ++s)
#pragma unroll
      for (int t = 0; t < 4; ++t) sacc[s][t] = (v4f){0.f, 0.f, 0.f, 0.f};
#pragma unroll
    for (int kf = 0; kf < 4; ++kf) {
#pragma unroll
      for (int t = 0; t < 4; ++t) {
        int ch = (t * 16 + l) * 16 + ((kf * 4 + q) ^ l);
        v8s bk = *(const v8s*)(Ks + ch * 16);
        sacc[0][t] = __builtin_amdgcn_mfma_f32_16x16x32_bf16(aq[0][kf], bk, sacc[0][t], 0, 0, 0);
        sacc[1][t] = __builtin_amdgcn_mfma_f32_16x16x32_bf16(aq[1][kf], bk, sacc[1][t], 0, 0, 0);
      }
    }
#pragma unroll
    for (int s = 0; s < 2; ++s) {
      float rmax[4], alpha[4], rsum[4];
#pragma unroll
      for (int r = 0; r < 4; ++r) {
        rmax[r] = fmaxf(fmaxf(sacc[s][0][r], sacc[s][1][r]),
                        fmaxf(sacc[s][2][r], sacc[s][3][r])) * SC;
#pragma unroll
        for (int msk = 1; msk < 16; msk <<= 1) rmax[r] = fmaxf(rmax[r], __shfl_xor(rmax[r], msk, 64));
        float mnew = fmaxf(mrow[s][r], rmax[r]);
        alpha[r] = __expf(mrow[s][r] - mnew);
        mrow[s][r] = mnew;
        rsum[r] = 0.f;
      }
#pragma unroll
      for (int t = 0; t < 4; ++t) {
#pragma unroll
        for (int r = 0; r < 4; ++r) {
          float p = __expf(sacc[s][t][r] * SC - mrow[s][r]);
          rsum[r] += p;
          pw[(s * 16 + q * 4 + r) * PROW + t * 16 + l] = f2bf(p);
        }
      }
#pragma unroll
      for (int r = 0; r < 4; ++r) {
#pragma unroll
        for (int msk = 1; msk < 16; msk <<= 1) rsum[r] += __shfl_xor(rsum[r], msk, 64);
        lrow[s][r] = lrow[s][r] * alpha[r] + rsum[r];
#pragma unroll
        for (int t = 0; t < 8; ++t) oacc[s][t][r] *= alpha[r];
      }
    }
#pragma unroll
    for (int s2 = 0; s2 < 2; ++s2) {
      v8s ap0 = *(const v8s*)(pw + l * PROW + s2 * 32 + q * 8);
      v8s ap1 = *(const v8s*)(pw + (16 + l) * PROW + s2 * 32 + q * 8);
#pragma unroll
      for (int t = 0; t < 8; ++t) {
        v8s bv = *(const v8s*)(Vt + (t * 16 + l) * VROW + s2 * 32 + q * 8);
        oacc[0][t] = __builtin_amdgcn_mfma_f32_16x16x32_bf16(ap0, bv, oacc[0][t], 0, 0, 0);
        oacc[1][t] = __builtin_amdgcn_mfma_f32_16x16x32_bf16(ap1, bv, oacc[1][t], 0, 0, 0);
      }
    }
    __syncthreads();
  }

  // epilogue: unnormalized O (fp32) + per-row (m,l)
#pragma unroll
  for (int s = 0; s < 2; ++s) {
#pragma unroll
    for (int t = 0; t < 8; ++t) {
#pragma unroll
      for (int r = 0; r < 4; ++r) {
        long grow = bb * 2048 + q0 + w * 32 + s * 16 + q * 4 + r;
        Opart[grow * 2048 + hh * 128 + t * 16 + l] = oacc[s][t][r];
      }
    }
    if (l == 0) {
#pragma unroll
      for (int r = 0; r < 4; ++r) {
        long grow = bb * 2048 + q0 + w * 32 + s * 16 + q * 4 + r;
        stats[((long)ks * 4096 + grow) * 16 + hh] = make_float2(mrow[s][r], lrow[s][r]);
      }
    }
  }
}

// ---------- combine the two K-split partials ----------
__global__ __launch_bounds__(256)
void attn_combine(const float* __restrict__ O0, const float* __restrict__ O1,
                  const float2* __restrict__ stats, unsigned short* __restrict__ o) {
  int grow = blockIdx.x, tid = threadIdx.x;
  int hh = tid >> 4;
  float2 s0 = stats[(long)grow * 16 + hh];
  float2 s1 = stats[((long)4096 + grow) * 16 + hh];
  float m = fmaxf(s0.x, s1.x);
  float e0 = __expf(s0.x - m), e1 = __expf(s1.x - m);
  float inv = 1.0f / (s0.y * e0 + s1.y * e1);
  long base = (long)grow * 2048 + tid * 8;
  float4 a0 = *(const float4*)(O0 + base), a1 = *(const float4*)(O0 + base + 4);
  float4 c0 = *(const float4*)(O1 + base), c1 = *(const float4*)(O1 + base + 4);
  unsigned short r[8];
  r[0] = f2bf((a0.x * e0 + c0.x * e1) * inv);
  r[1] = f2bf((a0.y * e0 + c0.y * e1) * inv);
  r[2] = f2bf((a0.z * e0 + c0.z * e1) * inv);
  r[3] = f2bf((a0.w * e0 + c0.w * e1) * inv);
  r[4] = f2bf((a1.x * e0 + c1.x * e1) * inv);
  r[5] = f2bf((a1.y * e0 + c1.y * e1) * inv);
  r[6] = f2bf((a1.z * e0 + c1.z * e1) * inv);
  r[7] = f2bf((a1.w * e0 + c1.w * e1) * inv);
  *(uint4*)(o + base) = *(uint4*)r;
}

extern "C" void kernel_launch(void* const* d_in, const int* in_sizes, int n_in,
                              void* d_out, int out_size, void* d_ws, size_t ws_size,
                              hipStream_t stream) {
  (void)in_sizes; (void)n_in; (void)out_size; (void)ws_size;
  const float* x      = (const float*)d_in[0];
  const float* w_qkv  = (const float*)d_in[1];
  const float* w_proj = (const float*)d_in[2];
  const float* w_fc1  = (const float*)d_in[3];
  const float* w_fc2  = (const float*)d_in[4];
  const float* g1 = (const float*)d_in[5];
  const float* b1 = (const float*)d_in[6];
  const float* g2 = (const float*)d_in[7];
  const float* b2 = (const float*)d_in[8];

  char* wsb = (char*)d_ws;
  float* acc = (float*)wsb;
  size_t off = 256;
  signed char* q8 = (signed char*)(wsb + off);       off += (size_t)4096 * 8192;
  float* invs = (float*)(wsb + off);                 off += 16384;
  signed char* wq_qkv = (signed char*)(wsb + off);   off += (size_t)6144 * 2048;
  signed char* wq_proj = (signed char*)(wsb + off);  off += (size_t)2048 * 2048;
  signed char* wq_fc1 = (signed char*)(wsb + off);   off += (size_t)8192 * 2048;
  signed char* wq_fc2 = (signed char*)(wsb + off);   off += (size_t)2048 * 8192;
  unsigned short* qkvh = (unsigned short*)(wsb + off); off += (size_t)4096 * 8192 * 2;
  unsigned short* obuf = (unsigned short*)(wsb + off); off += (size_t)4096 * 2048 * 2;
  float* x2 = (float*)(wsb + off);                   off += (size_t)4096 * 2048 * 4;
  float2* stats = (float2*)(wsb + off);              off += (size_t)2 * 4096 * 16 * 8;
  // K-split partial O buffers reuse dead regions: O0 = x2 (written later by proj),
  // O1 = q8 region (LN1 quants dead after qkv gemm; re-written by row_quant after combine)
  float* O0 = x2;
  float* O1 = (float*)q8;

  hipMemsetAsync(acc, 0, 256, stream);

  absum_kernel<<<dim3(1024), 256, 0, stream>>>(w_qkv, (long)6144 * 2048, acc + 0);
  absum_kernel<<<dim3(512),  256, 0, stream>>>(w_proj, (long)2048 * 2048, acc + 1);
  absum_kernel<<<dim3(1024), 256, 0, stream>>>(w_fc1, (long)8192 * 2048, acc + 2);
  absum_kernel<<<dim3(1024), 256, 0, stream>>>(w_fc2, (long)2048 * 8192, acc + 3);

  wquant_kernel<<<dim3(1024), 256, 0, stream>>>(w_qkv, (long)6144 * 2048 / 4, acc + 0, 12582912.f, wq_qkv, 11);
  wquant_kernel<<<dim3(1024), 256, 0, stream>>>(w_proj, (long)2048 * 2048 / 4, acc + 1, 4194304.f, wq_proj, 11);
  wquant_kernel<<<dim3(1024), 256, 0, stream>>>(w_fc1, (long)8192 * 2048 / 4, acc + 2, 16777216.f, wq_fc1, 11);
  wquant_kernel<<<dim3(1024), 256, 0, stream>>>(w_fc2, (long)2048 * 8192 / 4, acc + 3, 16777216.f, wq_fc2, 13);

  ln_quant_kernel<<<4096, 256, 0, stream>>>(x, g1, b1, q8, invs);
  gemm_i8<0><<<dim3(48, 32), 256, 0, stream>>>(q8, wq_qkv, 6144, 2048, acc + 0, 12582912.f, invs, nullptr, qkvh);
  fattn_kernel<<<dim3(16, 32, 2), 256, 0, stream>>>(qkvh, O0, O1, stats);
  attn_combine<<<4096, 256, 0, stream>>>(O0, O1, stats, obuf);
  row_quant_kernel<2048><<<4096, 256, 0, stream>>>(obuf, q8, invs);
  gemm_i8<1><<<dim3(16, 32), 256, 0, stream>>>(q8, wq_proj, 2048, 2048, acc + 1, 4194304.f, invs, x, x2);
  ln_quant_kernel<<<4096, 256, 0, stream>>>(x2, g2, b2, q8, invs);
  gemm_i8<2><<<dim3(64, 32), 256, 0, stream>>>(q8, wq_fc1, 8192, 2048, acc + 2, 16777216.f, invs, nullptr, qkvh);
  row_quant_kernel<8192><<<4096, 256, 0, stream>>>(qkvh, q8, invs);
  gemm_i8<1><<<dim3(16, 32), 256, 0, stream>>>(q8, wq_fc2, 2048, 8192, acc + 3, 16777216.f, invs, x2, (float*)d_out);
}

// Round 6
// 851.989 us; speedup vs baseline: 1.2756x; 1.0280x over previous
//
#include <hip/hip_runtime.h>
#include <cstdint>

#define DEVI __device__ __forceinline__

typedef int v4i __attribute__((ext_vector_type(4)));
typedef short v8s __attribute__((ext_vector_type(8)));
typedef float v4f __attribute__((ext_vector_type(4)));

// ---------- bf16 helpers (manual, RNE) ----------
DEVI float bf_lo(unsigned u) { return __uint_as_float(u << 16); }
DEVI float bf_hi(unsigned u) { return __uint_as_float(u & 0xffff0000u); }
DEVI float bf2f(unsigned short h) { return __uint_as_float(((unsigned)h) << 16); }
DEVI unsigned short f2bf(float f) {
  unsigned u = __float_as_uint(f);
  u += 0x7fffu + ((u >> 16) & 1u);
  return (unsigned short)(u >> 16);
}

// ---------- async global->LDS, 16B per lane (lane i lands at base + i*16) ----------
DEVI void async_copy16(void* l, const void* g) {
  __builtin_amdgcn_global_load_lds((const __attribute__((address_space(1))) void*)g,
                                   (__attribute__((address_space(3))) void*)l,
                                   16, 0, 0);
}

// ---------- wave (64-lane) reductions ----------
DEVI float wave_sum(float v) {
#pragma unroll
  for (int o = 32; o > 0; o >>= 1) v += __shfl_xor(v, o, 64);
  return v;
}
DEVI float wave_max(float v) {
#pragma unroll
  for (int o = 32; o > 0; o >>= 1) v = fmaxf(v, __shfl_xor(v, o, 64));
  return v;
}

// ---------- per-tensor sum(|w|) ----------
__global__ __launch_bounds__(256) void absum_kernel(const float* __restrict__ w, long n,
                                                    float* __restrict__ acc) {
  long stride = (long)gridDim.x * 1024;
  float s = 0.f;
  for (long i = ((long)blockIdx.x * 256 + threadIdx.x) * 4; i < n; i += stride) {
    float4 v = *(const float4*)(w + i);
    s += fabsf(v.x) + fabsf(v.y) + fabsf(v.z) + fabsf(v.w);
  }
  s = wave_sum(s);
  __shared__ float sc[4];
  int tid = threadIdx.x;
  if ((tid & 63) == 0) sc[tid >> 6] = s;
  __syncthreads();
  if (tid == 0) atomicAdd(acc, sc[0] + sc[1] + sc[2] + sc[3]);
}

// ---------- ternary weight quant into MFMA-fragment-major packed layout ----------
// packed block for (ntile, kb): 1024 B; chunk lane = (kgrp<<4)|(n&15) holds
// B[n][kb*64 + kgrp*16 .. +16]. A wave's b-frag load = contiguous 1 KB.
__global__ __launch_bounds__(256) void wquant_kernel(const float* __restrict__ w, long n4,
                                                     const float* __restrict__ acc, float cnt,
                                                     signed char* __restrict__ out, int kshift) {
  float wsv = fmaxf(acc[0] / cnt, 1e-5f);
  float inv = 1.0f / wsv;
  int K = 1 << kshift;
  long stride = (long)gridDim.x * 256;
  for (long i = (long)blockIdx.x * 256 + threadIdx.x; i < n4; i += stride) {
    float4 v = *(const float4*)(w + i * 4);
    int q0 = max(-1, min(1, (int)rintf(v.x * inv)));
    int q1 = max(-1, min(1, (int)rintf(v.y * inv)));
    int q2 = max(-1, min(1, (int)rintf(v.z * inv)));
    int q3 = max(-1, min(1, (int)rintf(v.w * inv)));
    unsigned r = (q0 & 0xff) | ((q1 & 0xff) << 8) | ((q2 & 0xff) << 16) | ((q3 & 0xff) << 24);
    long flat = i * 4;
    int n = (int)(flat >> kshift);
    int k = (int)(flat & (K - 1));
    long off = ((long)(n >> 4) * (K >> 6) + (k >> 6)) * 1024 +
               (((k >> 4) & 3) * 16 + (n & 15)) * 16 + (k & 15);
    *(unsigned*)(out + off) = r;
  }
}

// ---------- fused LayerNorm + per-token absmax int8 quant (C=2048, 1 block/row) ----------
__global__ __launch_bounds__(256) void ln_quant_kernel(const float* __restrict__ x,
                                                       const float* __restrict__ g,
                                                       const float* __restrict__ b,
                                                       signed char* __restrict__ q,
                                                       float* __restrict__ inv_s) {
  int row = blockIdx.x, tid = threadIdx.x;
  const float4* xr = (const float4*)(x + (long)row * 2048);
  float4 a0 = xr[tid * 2], a1 = xr[tid * 2 + 1];
  float xv[8] = {a0.x, a0.y, a0.z, a0.w, a1.x, a1.y, a1.z, a1.w};
  float s = 0.f, s2 = 0.f;
#pragma unroll
  for (int e = 0; e < 8; ++e) { s += xv[e]; s2 += xv[e] * xv[e]; }
  s = wave_sum(s); s2 = wave_sum(s2);
  __shared__ float sc[8];
  if ((tid & 63) == 0) { sc[tid >> 6] = s; sc[4 + (tid >> 6)] = s2; }
  __syncthreads();
  float mean = (sc[0] + sc[1] + sc[2] + sc[3]) * (1.f / 2048.f);
  float var = (sc[4] + sc[5] + sc[6] + sc[7]) * (1.f / 2048.f) - mean * mean;
  float rs = 1.0f / sqrtf(var + 1e-5f);
  float4 g0 = ((const float4*)g)[tid * 2], g1v = ((const float4*)g)[tid * 2 + 1];
  float4 b0 = ((const float4*)b)[tid * 2], b1v = ((const float4*)b)[tid * 2 + 1];
  float gv[8] = {g0.x, g0.y, g0.z, g0.w, g1v.x, g1v.y, g1v.z, g1v.w};
  float bv[8] = {b0.x, b0.y, b0.z, b0.w, b1v.x, b1v.y, b1v.z, b1v.w};
  float y[8];
  float am = 0.f;
#pragma unroll
  for (int e = 0; e < 8; ++e) {
    y[e] = (xv[e] - mean) * rs * gv[e] + bv[e];
    am = fmaxf(am, fabsf(y[e]));
  }
  am = wave_max(am);
  __syncthreads();
  if ((tid & 63) == 0) sc[tid >> 6] = am;
  __syncthreads();
  am = fmaxf(fmaxf(sc[0], sc[1]), fmaxf(sc[2], sc[3]));
  float c = fmaxf(am, 1e-5f);
  float xs = 127.0f / c;
  union { signed char c8[8]; int2 v; } u;
#pragma unroll
  for (int e = 0; e < 8; ++e) {
    int t = (int)rintf(y[e] * xs);
    u.c8[e] = (signed char)max(-128, min(127, t));
  }
  ((int2*)(q + (long)row * 2048))[tid] = u.v;
  if (tid == 0) inv_s[row] = c * (1.0f / 127.0f);
}

// ---------- per-row absmax int8 quant from bf16 rows (R = 2048 or 8192) ----------
template <int R>
__global__ __launch_bounds__(256) void row_quant_kernel(const unsigned short* __restrict__ in,
                                                        signed char* __restrict__ q,
                                                        float* __restrict__ inv_s) {
  constexpr int V = R / 2048;
  int row = blockIdx.x, tid = threadIdx.x;
  const uint4* p = (const uint4*)(in + (long)row * R);
  float y[V * 8];
  float am = 0.f;
#pragma unroll
  for (int v = 0; v < V; ++v) {
    uint4 d = p[tid * V + v];
    unsigned xw[4] = {d.x, d.y, d.z, d.w};
#pragma unroll
    for (int k = 0; k < 4; ++k) {
      y[v * 8 + k * 2] = bf_lo(xw[k]);
      y[v * 8 + k * 2 + 1] = bf_hi(xw[k]);
    }
  }
#pragma unroll
  for (int e = 0; e < V * 8; ++e) am = fmaxf(am, fabsf(y[e]));
  am = wave_max(am);
  __shared__ float sc[4];
  if ((tid & 63) == 0) sc[tid >> 6] = am;
  __syncthreads();
  am = fmaxf(fmaxf(sc[0], sc[1]), fmaxf(sc[2], sc[3]));
  float c = fmaxf(am, 1e-5f);
  float xs = 127.0f / c;
  signed char* qr = q + (long)row * R;
#pragma unroll
  for (int v = 0; v < V; ++v) {
    union { signed char c8[8]; long l; } u;
#pragma unroll
    for (int k = 0; k < 8; ++k) {
      int t = (int)rintf(y[v * 8 + k] * xs);
      u.c8[k] = (signed char)max(-128, min(127, t));
    }
    ((long*)qr)[tid * V + v] = u.l;
  }
  if (tid == 0) inv_s[row] = c * (1.0f / 127.0f);
}

// ---------- int8 MFMA GEMM v4: BK=128, A dbuf (XOR-swizzled chunks, 1 barrier/iter),
// packed-B coalesced 1KB loads prefetched 1 iter ahead; 1D grid, XCD swizzle (n%8 = xcd).
template <int EPI>
__global__ __launch_bounds__(256)
void gemm_i8(const signed char* __restrict__ A, const signed char* __restrict__ Bp,
             int N, int K, const float* __restrict__ wacc, float wcount,
             const float* __restrict__ inv_s, const float* __restrict__ res,
             void* __restrict__ outp) {
  __shared__ signed char As[2][128 * 128];
  int tid = threadIdx.x;
  // decode: idx = (n&7) + 8*((n>>3)*32 + m)   [NB % 8 == 0, MB = 32]
  int idx = blockIdx.x;
  int r8 = idx & 7, rest = idx >> 3;
  int mb = rest & 31;
  int nb = (rest >> 5) * 8 + r8;
  int m0 = mb * 128, n0 = nb * 128;
  int w = tid >> 6, lane = tid & 63;
  int wm = (w >> 1) * 64, wn = (w & 1) * 64;
  int lr = lane & 15, q = lane >> 4;

  v4i acc[4][4] = {};

  // A staging: tile is 128 rows x 8 chunks(16B); LDS chunk u = row*8 + (cg ^ (row&7)).
  // wave w stages rows [w*32, w*32+32), instr i covers rows +i*8; lane -> row w*32+i*8+(lane>>3),
  // source chunk col = (lane&7) ^ ((lane>>3)&7); LDS base (wave-uniform) = (w*256+i*64)*16.
  int srow = w * 32 + (lane >> 3);
  int scol = (lane & 7) ^ ((lane >> 3) & 7);
  const signed char* ga = A + (long)(m0 + srow) * K + scol * 16;

  int nkb = K >> 7;  // BK=128 iterations
  // B packed-fragment pointers: contiguous 1KB per (ntile, kb64)
  const signed char* gbp[4];
#pragma unroll
  for (int t = 0; t < 4; ++t) {
    int ntile = (n0 >> 4) + (w & 1) * 4 + t;
    gbp[t] = Bp + (long)ntile * (K >> 6) * 1024 + lane * 16;
  }

  // prologue: stage A tile 0, load B frags for tile 0
  v4i bf_cur[2][4], bf_nxt[2][4];
#pragma unroll
  for (int i = 0; i < 4; ++i)
    async_copy16(&As[0][(w * 256 + i * 64) * 16], ga + i * 8 * K);
#pragma unroll
  for (int s = 0; s < 2; ++s)
#pragma unroll
    for (int t = 0; t < 4; ++t) bf_cur[s][t] = *(const v4i*)(gbp[t] + s * 1024);
  __syncthreads();

  int buf = 0;
  for (int kb = 0; kb < nkb; ++kb) {
    if (kb + 1 < nkb) {
#pragma unroll
      for (int i = 0; i < 4; ++i)
        async_copy16(&As[buf ^ 1][(w * 256 + i * 64) * 16], ga + i * 8 * K + (kb + 1) * 128);
#pragma unroll
      for (int s = 0; s < 2; ++s)
#pragma unroll
        for (int t = 0; t < 4; ++t)
          bf_nxt[s][t] = *(const v4i*)(gbp[t] + ((kb + 1) * 2 + s) * 1024);
    }
#pragma unroll
    for (int s = 0; s < 2; ++s) {
      v4i af[4];
#pragma unroll
      for (int i = 0; i < 4; ++i) {
        int row = wm + i * 16 + lr;
        af[i] = *(const v4i*)(&As[buf][(row * 8 + ((s * 4 + q) ^ (lr & 7))) * 16]);
      }
#pragma unroll
      for (int i = 0; i < 4; ++i)
#pragma unroll
        for (int j = 0; j < 4; ++j)
          acc[i][j] = __builtin_amdgcn_mfma_i32_16x16x64_i8(af[i], bf_cur[s][j], acc[i][j], 0, 0, 0);
    }
    __syncthreads();  // As[buf] reads done; next-tile staging (in flight during MFMA) drained
    if (kb + 1 < nkb) {
#pragma unroll
      for (int s = 0; s < 2; ++s)
#pragma unroll
        for (int t = 0; t < 4; ++t) bf_cur[s][t] = bf_nxt[s][t];
    }
    buf ^= 1;
  }

  float wsv = fmaxf(wacc[0] / wcount, 1e-5f);
#pragma unroll
  for (int i = 0; i < 4; ++i) {
    int rowbase = m0 + wm + i * 16 + (lane >> 4) * 4;
#pragma unroll
    for (int r = 0; r < 4; ++r) {
      int row = rowbase + r;
      float s = wsv * inv_s[row];
#pragma unroll
      for (int j = 0; j < 4; ++j) {
        int col = n0 + wn + j * 16 + (lane & 15);
        long off = (long)row * N + col;
        float v = (float)acc[i][j][r] * s;
        if constexpr (EPI == 0) {
          ((unsigned short*)outp)[off] = f2bf(v);
        } else if constexpr (EPI == 1) {
          ((float*)outp)[off] = v + res[off];
        } else {
          float gvv = 0.5f * v * (1.0f + erff(v * 0.70710678118654752f));
          ((unsigned short*)outp)[off] = f2bf(gvv);
        }
      }
    }
  }
}

// ---------- MFMA flash attention, K-split partials, XCD-swizzled 1D grid ----------
// idx = (bh&7) + 8*((bh>>3)*32 + qt*2 + ks): all 32 blocks of one bh share an XCD (K/V L2-resident)
__global__ __launch_bounds__(256, 2)
void fattn_kernel(const unsigned short* __restrict__ qkv, float* __restrict__ O0,
                  float* __restrict__ O1, float2* __restrict__ stats) {
  constexpr int VROW = 72;
  constexpr int PROW = 72;
  __shared__ char Ks[16384];
  __shared__ unsigned short Vt[128 * VROW];
  __shared__ unsigned short Ps[4 * 32 * PROW];

  int tid = threadIdx.x;
  int w = tid >> 6, lane = tid & 63;
  int l = lane & 15, q = lane >> 4;
  int idx = blockIdx.x;
  int r8 = idx & 7, rest = idx >> 3;
  int ks = rest & 1;
  int qt = (rest >> 1) & 15;
  int bh = (rest >> 5) * 8 + r8;
  int bb = bh >> 4, hh = bh & 15;
  const unsigned short* base = qkv + (long)bb * 2048 * 6144;
  int q0 = qt * 128;
  float* Opart = ks ? O1 : O0;

  v8s aq[2][4];
#pragma unroll
  for (int s = 0; s < 2; ++s) {
    const unsigned short* qrow = base + (long)(q0 + w * 32 + s * 16 + l) * 6144 + hh * 128;
#pragma unroll
    for (int kf = 0; kf < 4; ++kf) aq[s][kf] = *(const v8s*)(qrow + kf * 32 + q * 8);
  }

  v4f oacc[2][8];
#pragma unroll
  for (int s = 0; s < 2; ++s)
#pragma unroll
    for (int t = 0; t < 8; ++t) oacc[s][t] = (v4f){0.f, 0.f, 0.f, 0.f};
  float mrow[2][4], lrow[2][4];
#pragma unroll
  for (int s = 0; s < 2; ++s)
#pragma unroll
    for (int r = 0; r < 4; ++r) { mrow[s][r] = -1e30f; lrow[s][r] = 0.f; }

  unsigned short* pw = Ps + w * 32 * PROW;
  const unsigned short* kbase_g = base + 2048 + hh * 128;
  const unsigned short* vbase_g = base + 4096 + hh * 128;
  int kg = tid & 7, dg = tid >> 3;
  constexpr float SC = 0.08838834764831845f;

  for (int kt = ks * 16; kt < ks * 16 + 16; ++kt) {
    int k0 = kt * 64;
#pragma unroll
    for (int i = 0; i < 4; ++i) {
      int c = i * 256 + w * 64 + lane;
      int key = c >> 4;
      int dch = (c & 15) ^ (key & 15);
      async_copy16(Ks + (i * 256 + w * 64) * 16,
                   kbase_g + (long)(k0 + key) * 6144 + dch * 8);
    }
    {
      uint2 lv[8];
#pragma unroll
      for (int i = 0; i < 8; ++i)
        lv[i] = *(const uint2*)(vbase_g + (long)(k0 + kg * 8 + i) * 6144 + dg * 4);
#pragma unroll
      for (int jd = 0; jd < 4; ++jd) {
        v8s pk;
#pragma unroll
        for (int i = 0; i < 8; ++i) {
          unsigned word = (jd < 2) ? lv[i].x : lv[i].y;
          pk[i] = (short)((jd & 1) ? (word >> 16) : (word & 0xffffu));
        }
        *(v8s*)(Vt + (dg * 4 + jd) * VROW + kg * 8) = pk;
      }
    }
    __syncthreads();

    v4f sacc[2][4];
#pragma unroll
    for (int s = 0; s < 2; ++s)
#pragma unroll
      for (int t = 0; t < 4; ++t) sacc[s][t] = (v4f){0.f, 0.f, 0.f, 0.f};
#pragma unroll
    for (int kf = 0; kf < 4; ++kf) {
#pragma unroll
      for (int t = 0; t < 4; ++t) {
        int ch = (t * 16 + l) * 16 + ((kf * 4 + q) ^ l);
        v8s bk = *(const v8s*)(Ks + ch * 16);
        sacc[0][t] = __builtin_amdgcn_mfma_f32_16x16x32_bf16(aq[0][kf], bk, sacc[0][t], 0, 0, 0);
        sacc[1][t] = __builtin_amdgcn_mfma_f32_16x16x32_bf16(aq[1][kf], bk, sacc[1][t], 0, 0, 0);
      }
    }
#pragma unroll
    for (int s = 0; s < 2; ++s) {
      float rmax[4], alpha[4], rsum[4];
#pragma unroll
      for (int r = 0; r < 4; ++r) {
        rmax[r] = fmaxf(fmaxf(sacc[s][0][r], sacc[s][1][r]),
                        fmaxf(sacc[s][2][r], sacc[s][3][r])) * SC;
#pragma unroll
        for (int msk = 1; msk < 16; msk <<= 1) rmax[r] = fmaxf(rmax[r], __shfl_xor(rmax[r], msk, 64));
        float mnew = fmaxf(mrow[s][r], rmax[r]);
        alpha[r] = __expf(mrow[s][r] - mnew);
        mrow[s][r] = mnew;
        rsum[r] = 0.f;
      }
#pragma unroll
      for (int t = 0; t < 4; ++t) {
#pragma unroll
        for (int r = 0; r < 4; ++r) {
          float p = __expf(sacc[s][t][r] * SC - mrow[s][r]);
          rsum[r] += p;
          pw[(s * 16 + q * 4 + r) * PROW + t * 16 + l] = f2bf(p);
        }
      }
#pragma unroll
      for (int r = 0; r < 4; ++r) {
#pragma unroll
        for (int msk = 1; msk < 16; msk <<= 1) rsum[r] += __shfl_xor(rsum[r], msk, 64);
        lrow[s][r] = lrow[s][r] * alpha[r] + rsum[r];
#pragma unroll
        for (int t = 0; t < 8; ++t) oacc[s][t][r] *= alpha[r];
      }
    }
#pragma unroll
    for (int s2 = 0; s2 < 2; ++s2) {
      v8s ap0 = *(const v8s*)(pw + l * PROW + s2 * 32 + q * 8);
      v8s ap1 = *(const v8s*)(pw + (16 + l) * PROW + s2 * 32 + q * 8);
#pragma unroll
      for (int t = 0; t < 8; ++t) {
        v8s bv = *(const v8s*)(Vt + (t * 16 + l) * VROW + s2 * 32 + q * 8);
        oacc[0][t] = __builtin_amdgcn_mfma_f32_16x16x32_bf16(ap0, bv, oacc[0][t], 0, 0, 0);
        oacc[1][t] = __builtin_amdgcn_mfma_f32_16x16x32_bf16(ap1, bv, oacc[1][t], 0, 0, 0);
      }
    }
    __syncthreads();
  }

  // epilogue: unnormalized O (fp32) + per-row (m,l)
#pragma unroll
  for (int s = 0; s < 2; ++s) {
#pragma unroll
    for (int t = 0; t < 8; ++t) {
#pragma unroll
      for (int r = 0; r < 4; ++r) {
        long grow = bb * 2048 + q0 + w * 32 + s * 16 + q * 4 + r;
        Opart[grow * 2048 + hh * 128 + t * 16 + l] = oacc[s][t][r];
      }
    }
    if (l == 0) {
#pragma unroll
      for (int r = 0; r < 4; ++r) {
        long grow = bb * 2048 + q0 + w * 32 + s * 16 + q * 4 + r;
        stats[((long)ks * 4096 + grow) * 16 + hh] = make_float2(mrow[s][r], lrow[s][r]);
      }
    }
  }
}

// ---------- combine the two K-split partials ----------
__global__ __launch_bounds__(256)
void attn_combine(const float* __restrict__ O0, const float* __restrict__ O1,
                  const float2* __restrict__ stats, unsigned short* __restrict__ o) {
  int grow = blockIdx.x, tid = threadIdx.x;
  int hh = tid >> 4;
  float2 s0 = stats[(long)grow * 16 + hh];
  float2 s1 = stats[((long)4096 + grow) * 16 + hh];
  float m = fmaxf(s0.x, s1.x);
  float e0 = __expf(s0.x - m), e1 = __expf(s1.x - m);
  float inv = 1.0f / (s0.y * e0 + s1.y * e1);
  long base = (long)grow * 2048 + tid * 8;
  float4 a0 = *(const float4*)(O0 + base), a1 = *(const float4*)(O0 + base + 4);
  float4 c0 = *(const float4*)(O1 + base), c1 = *(const float4*)(O1 + base + 4);
  unsigned short r[8];
  r[0] = f2bf((a0.x * e0 + c0.x * e1) * inv);
  r[1] = f2bf((a0.y * e0 + c0.y * e1) * inv);
  r[2] = f2bf((a0.z * e0 + c0.z * e1) * inv);
  r[3] = f2bf((a0.w * e0 + c0.w * e1) * inv);
  r[4] = f2bf((a1.x * e0 + c1.x * e1) * inv);
  r[5] = f2bf((a1.y * e0 + c1.y * e1) * inv);
  r[6] = f2bf((a1.z * e0 + c1.z * e1) * inv);
  r[7] = f2bf((a1.w * e0 + c1.w * e1) * inv);
  *(uint4*)(o + base) = *(uint4*)r;
}

extern "C" void kernel_launch(void* const* d_in, const int* in_sizes, int n_in,
                              void* d_out, int out_size, void* d_ws, size_t ws_size,
                              hipStream_t stream) {
  (void)in_sizes; (void)n_in; (void)out_size; (void)ws_size;
  const float* x      = (const float*)d_in[0];
  const float* w_qkv  = (const float*)d_in[1];
  const float* w_proj = (const float*)d_in[2];
  const float* w_fc1  = (const float*)d_in[3];
  const float* w_fc2  = (const float*)d_in[4];
  const float* g1 = (const float*)d_in[5];
  const float* b1 = (const float*)d_in[6];
  const float* g2 = (const float*)d_in[7];
  const float* b2 = (const float*)d_in[8];

  char* wsb = (char*)d_ws;
  float* acc = (float*)wsb;
  size_t off = 256;
  signed char* q8 = (signed char*)(wsb + off);       off += (size_t)4096 * 8192;
  float* invs = (float*)(wsb + off);                 off += 16384;
  signed char* wq_qkv = (signed char*)(wsb + off);   off += (size_t)6144 * 2048;
  signed char* wq_proj = (signed char*)(wsb + off);  off += (size_t)2048 * 2048;
  signed char* wq_fc1 = (signed char*)(wsb + off);   off += (size_t)8192 * 2048;
  signed char* wq_fc2 = (signed char*)(wsb + off);   off += (size_t)2048 * 8192;
  unsigned short* qkvh = (unsigned short*)(wsb + off); off += (size_t)4096 * 8192 * 2;
  unsigned short* obuf = (unsigned short*)(wsb + off); off += (size_t)4096 * 2048 * 2;
  float* x2 = (float*)(wsb + off);                   off += (size_t)4096 * 2048 * 4;
  float2* stats = (float2*)(wsb + off);              off += (size_t)2 * 4096 * 16 * 8;
  float* O0 = x2;           // dead until proj writes it
  float* O1 = (float*)q8;   // LN1 quants dead after qkv gemm

  hipMemsetAsync(acc, 0, 256, stream);

  absum_kernel<<<dim3(1024), 256, 0, stream>>>(w_qkv, (long)6144 * 2048, acc + 0);
  absum_kernel<<<dim3(512),  256, 0, stream>>>(w_proj, (long)2048 * 2048, acc + 1);
  absum_kernel<<<dim3(1024), 256, 0, stream>>>(w_fc1, (long)8192 * 2048, acc + 2);
  absum_kernel<<<dim3(1024), 256, 0, stream>>>(w_fc2, (long)2048 * 8192, acc + 3);

  wquant_kernel<<<dim3(1024), 256, 0, stream>>>(w_qkv, (long)6144 * 2048 / 4, acc + 0, 12582912.f, wq_qkv, 11);
  wquant_kernel<<<dim3(1024), 256, 0, stream>>>(w_proj, (long)2048 * 2048 / 4, acc + 1, 4194304.f, wq_proj, 11);
  wquant_kernel<<<dim3(1024), 256, 0, stream>>>(w_fc1, (long)8192 * 2048 / 4, acc + 2, 16777216.f, wq_fc1, 11);
  wquant_kernel<<<dim3(1024), 256, 0, stream>>>(w_fc2, (long)2048 * 8192 / 4, acc + 3, 16777216.f, wq_fc2, 13);

  ln_quant_kernel<<<4096, 256, 0, stream>>>(x, g1, b1, q8, invs);
  gemm_i8<0><<<48 * 32, 256, 0, stream>>>(q8, wq_qkv, 6144, 2048, acc + 0, 12582912.f, invs, nullptr, qkvh);
  fattn_kernel<<<1024, 256, 0, stream>>>(qkvh, O0, O1, stats);
  attn_combine<<<4096, 256, 0, stream>>>(O0, O1, stats, obuf);
  row_quant_kernel<2048><<<4096, 256, 0, stream>>>(obuf, q8, invs);
  gemm_i8<1><<<16 * 32, 256, 0, stream>>>(q8, wq_proj, 2048, 2048, acc + 1, 4194304.f, invs, x, x2);
  ln_quant_kernel<<<4096, 256, 0, stream>>>(x2, g2, b2, q8, invs);
  gemm_i8<2><<<64 * 32, 256, 0, stream>>>(q8, wq_fc1, 8192, 2048, acc + 2, 16777216.f, invs, nullptr, qkvh);
  row_quant_kernel<8192><<<4096, 256, 0, stream>>>(qkvh, q8, invs);
  gemm_i8<1><<<16 * 32, 256, 0, stream>>>(q8, wq_fc2, 2048, 8192, acc + 3, 16777216.f, invs, x2, (float*)d_out);
}